// Round 5
// baseline (357.839 us; speedup 1.0000x reference)
//
#include <hip/hip_runtime.h>
#include <hip/hip_bf16.h>
#include <stdint.h>

#define T_SEQ 4096
#define NH 12
#define HD 64
#define ED 768
#define N_QKV 2304

typedef short bf16x8 __attribute__((ext_vector_type(8)));
typedef float f32x4 __attribute__((ext_vector_type(4)));
typedef float f32x16 __attribute__((ext_vector_type(16)));

#define GLDS16(gsrc, ldst) \
  __builtin_amdgcn_global_load_lds((const __attribute__((address_space(1))) unsigned int*)(gsrc), \
                                   (__attribute__((address_space(3))) unsigned int*)(ldst), 16, 0, 0)

__device__ __forceinline__ unsigned short f2bf(float f) {
  unsigned int u = __float_as_uint(f);
  unsigned int r = (u + 0x7FFFu + ((u >> 16) & 1u)) >> 16;
  return (unsigned short)r;
}
__device__ __forceinline__ float bf2f(unsigned short u) {
  return __uint_as_float((unsigned int)u << 16);
}
__device__ __forceinline__ unsigned int pk2(float a, float b) {
  __hip_bfloat162 h = __float22bfloat162_rn(make_float2(a, b));
  union { __hip_bfloat162 h; unsigned int u; } c; c.h = h; return c.u;
}

// ---------------- convert: f32 -> bf16 for x, Wqkv(concat), Wo; bias concat ----
__global__ void convert_kernel(const float* __restrict__ x,
                               const float* __restrict__ wq, const float* __restrict__ wk,
                               const float* __restrict__ wv, const float* __restrict__ wo,
                               const float* __restrict__ bq, const float* __restrict__ bk,
                               const float* __restrict__ bv,
                               unsigned short* __restrict__ xb, unsigned short* __restrict__ wb,
                               unsigned short* __restrict__ wob, float* __restrict__ biasc)
{
  const int NX = T_SEQ * ED;   // 3145728
  const int NW = ED * ED;      // 589824
  int i = blockIdx.x * blockDim.x + threadIdx.x;
  if (i < NX) { xb[i] = f2bf(x[i]); return; }
  i -= NX;
  if (i < 3 * NW) {
    const float* w = (i < NW) ? wq : ((i < 2 * NW) ? wk : wv);
    wb[i] = f2bf(w[i % NW]);
    return;
  }
  i -= 3 * NW;
  if (i < NW) { wob[i] = f2bf(wo[i]); return; }
  i -= NW;
  if (i < N_QKV) {
    biasc[i] = (i < ED) ? bq[i] : ((i < 2 * ED) ? bk[i - ED] : bv[i - 2 * ED]);
  }
}

// ---------------- bf16 NT GEMM: C = A[M][K] * B[N][K]^T + bias ------------------
// 128x128 tile, BK=64, 4 waves. Staging via global_load_lds (16B) with the global
// source slot pre-swizzled so linear LDS writes land XOR-swizzled (rule #21):
// LDS(row, pos) holds global slot pos^(row&7); reads use slot j at pos j^(row&7).
template <int OUT_BF16>
__global__ __launch_bounds__(256) void gemm_bf16nt(const unsigned short* __restrict__ A,
                                                   const unsigned short* __restrict__ B,
                                                   const float* __restrict__ bias,
                                                   void* __restrict__ Cout,
                                                   int M, int N, int K, int ldc)
{
  __shared__ unsigned short As[128 * 64];
  __shared__ unsigned short Bs[128 * 64];
  int nb = N >> 7;
  int mt = blockIdx.x / nb, nt = blockIdx.x % nb;
  int m0 = mt << 7, n0 = nt << 7;
  int tid = threadIdx.x;
  int w = tid >> 6, lane = tid & 63;
  int g = lane >> 4, q15 = lane & 15;
  int wm = w >> 1, wn = w & 1;
  int rch = lane >> 3;              // row within 8-row chunk
  int ssw = (lane & 7) ^ rch;       // pre-swizzled source slot

  f32x4 acc[4][4] = {};
  const unsigned short* Abase = A + (size_t)(m0 + rch) * K + ssw * 8;
  const unsigned short* Bbase = B + (size_t)(n0 + rch) * K + ssw * 8;

  int nK = K >> 6;
  for (int kt = 0; kt < nK; ++kt) {
    int k0 = kt << 6;
#pragma unroll
    for (int i = 0; i < 4; ++i) {
      int c = w * 4 + i;            // 16 A-chunks, 16 B-chunks of 1KB (8 rows)
      GLDS16(Abase + (size_t)c * 8 * K + k0, As + c * 512);
      GLDS16(Bbase + (size_t)c * 8 * K + k0, Bs + c * 512);
    }
    __syncthreads();                 // drains vmcnt -> LDS tile ready
#pragma unroll
    for (int h = 0; h < 2; ++h) {
      bf16x8 af[4], bfr[4];
#pragma unroll
      for (int i = 0; i < 4; ++i) {
        int row = wm * 64 + i * 16 + q15;
        af[i] = *(const bf16x8*)((const char*)As + row * 128 + (((4 * h + g) ^ (row & 7)) << 4));
        int col = wn * 64 + i * 16 + q15;
        bfr[i] = *(const bf16x8*)((const char*)Bs + col * 128 + (((4 * h + g) ^ (col & 7)) << 4));
      }
#pragma unroll
      for (int i = 0; i < 4; ++i)
#pragma unroll
        for (int j = 0; j < 4; ++j)
          acc[i][j] = __builtin_amdgcn_mfma_f32_16x16x32_bf16(af[i], bfr[j], acc[i][j], 0, 0, 0);
    }
    __syncthreads();                 // all waves done reading before next overwrite
  }
#pragma unroll
  for (int j = 0; j < 4; ++j) {
    int col = n0 + wn * 64 + j * 16 + q15;
    float bv = bias[col];
#pragma unroll
    for (int i = 0; i < 4; ++i) {
      int rowb = m0 + wm * 64 + i * 16 + 4 * g;
#pragma unroll
      for (int r = 0; r < 4; ++r) {
        float val = acc[i][j][r] + bv;
        if constexpr (OUT_BF16)
          ((unsigned short*)Cout)[(size_t)(rowb + r) * ldc + col] = f2bf(val);
        else
          ((float*)Cout)[(size_t)(rowb + r) * ldc + col] = val;
      }
    }
  }
}

// ---------------- prep: fused RoPE(q,k) + V transpose, bf16 in/out --------------
// Block = (head, 64-t chunk). LDS sincos table computed once, used for q and k.
// Q additionally scaled by 0.125*log2(e) (softmax runs in exp2 domain).
__global__ __launch_bounds__(256) void prep_kernel(const unsigned short* __restrict__ qkvb,
                                                   unsigned short* __restrict__ qr,
                                                   unsigned short* __restrict__ kr,
                                                   unsigned short* __restrict__ vT)
{
  __shared__ float2 tab[2048];              // [t_local 64][idx 32]
  __shared__ unsigned short vtile[64][66];  // [d][t_local], padded
  int head = blockIdx.x / 64;
  int t0 = (blockIdx.x % 64) * 64;
  int tid = threadIdx.x;
#pragma unroll
  for (int i = 0; i < 8; ++i) {
    int e = tid + i * 256;
    int tl = e >> 5, idx = e & 31;
    float inv = exp2f((float)idx * (-13.287712379549449f / 32.0f)); // 10000^(-idx/32)
    float ang = (float)(t0 + tl) * inv;
    float s, c;
    sincosf(ang, &s, &c);
    tab[e] = make_float2(s, c);
  }
  {
    int d = tid & 63, rr = tid >> 6;
#pragma unroll
    for (int i = 0; i < 16; ++i) {
      int row = rr * 16 + i;
      vtile[d][row] = qkvb[(size_t)(t0 + row) * N_QKV + 2 * ED + head * HD + d];
    }
  }
  __syncthreads();
  const float SCQ = 0.18033688011112042f;   // 0.125 * log2(e)
#pragma unroll
  for (int i = 0; i < 8; ++i) {
    int e = tid + i * 256;
    int tl = e >> 5, idx = e & 31;
    int row = t0 + tl;
    const unsigned short* src = qkvb + (size_t)row * N_QKV + head * HD;
    float2 sc = tab[e];
    float x1 = bf2f(src[idx]), x2 = bf2f(src[idx + 32]);
    unsigned short* o = qr + ((size_t)head * T_SEQ + row) * HD + idx;
    o[0]  = f2bf((x1 * sc.y - x2 * sc.x) * SCQ);
    o[32] = f2bf((x1 * sc.x + x2 * sc.y) * SCQ);
    x1 = bf2f(src[ED + idx]); x2 = bf2f(src[ED + idx + 32]);
    o = kr + ((size_t)head * T_SEQ + row) * HD + idx;
    o[0]  = f2bf(x1 * sc.y - x2 * sc.x);
    o[32] = f2bf(x1 * sc.x + x2 * sc.y);
  }
  {
    int tl = tid & 63, rr = tid >> 6;
#pragma unroll
    for (int i = 0; i < 16; ++i) {
      int d = rr * 16 + i;
      vT[((size_t)head * HD + d) * T_SEQ + t0 + tl] = vtile[d][tl];
    }
  }
}

// ---------------- Flash attention: 1 wave = 32 q rows, 32x32 MFMA, no LDS ------
// S^T = mfma_32x32x16(K, Q): lane holds S[key=32b+(r&3)+8*(r>>2)+4*hi][q=l&31].
// Softmax lane-local (log2 domain) + one shfl_xor(32). P redistributed to the PV
// A-fragment via cvt_pk + shfl_xor(32) + per-half selects (correct by
// construction; permlane32_swap variant had its halves crossed). K/V frags read
// directly from global (per-head K/V = 1MB, L2-resident). No barriers, no LDS.
__global__ __launch_bounds__(64) void attn_kernel(const unsigned short* __restrict__ qr,
                                                  const unsigned short* __restrict__ kr,
                                                  const unsigned short* __restrict__ vT,
                                                  const float* __restrict__ mask,
                                                  unsigned short* __restrict__ ctx)
{
  int head = blockIdx.x >> 7;          // 128 q-blocks of 32 per head
  int q0 = (blockIdx.x & 127) << 5;
  int lane = threadIdx.x;
  int l31 = lane & 31, hi = lane >> 5;

  // Q fragments: B-operand, col q = l31, d-elems = ds*16 + hi*8 + j
  const unsigned short* qb = qr + ((size_t)head * T_SEQ + q0 + l31) * HD + hi * 8;
  bf16x8 qf[4];
#pragma unroll
  for (int ds = 0; ds < 4; ++ds) qf[ds] = *(const bf16x8*)(qb + ds * 16);

  // mask fast path: skip bias adds when mask is all ones
  bool masked;
  {
    int ok = 1;
    const f32x4* m4 = (const f32x4*)mask;
#pragma unroll
    for (int i = 0; i < 16; ++i) {
      f32x4 v = m4[lane + i * 64];
      ok &= (int)(v[0] == 1.f) & (int)(v[1] == 1.f) & (int)(v[2] == 1.f) & (int)(v[3] == 1.f);
    }
    masked = (__all(ok) == 0);
  }

  const unsigned short* kbase = kr + ((size_t)head * T_SEQ + l31) * HD + hi * 8;
  const unsigned short* vbase = vT + ((size_t)head * HD + l31) * T_SEQ + hi * 8;

  f32x16 acc0 = {}, acc1 = {};
  float m_run = -1e30f, l_run = 0.f;

  for (int kv = 0; kv < T_SEQ / 64; ++kv) {
    int k0 = kv << 6;
    // K frags: A-operand, row key = 32b + l31, d-elems = ds*16 + hi*8 + j
    bf16x8 kf[2][4];
#pragma unroll
    for (int b = 0; b < 2; ++b)
#pragma unroll
      for (int ds = 0; ds < 4; ++ds)
        kf[b][ds] = *(const bf16x8*)(kbase + (size_t)(k0 + b * 32) * HD + ds * 16);
    // V frags: B-operand, col d = 32*dt + l31, k-elems = ks*16 + hi*8 + j
    bf16x8 vf[2][4];
#pragma unroll
    for (int dt = 0; dt < 2; ++dt)
#pragma unroll
      for (int ks = 0; ks < 4; ++ks)
        vf[dt][ks] = *(const bf16x8*)(vbase + (size_t)(dt * 32) * T_SEQ + k0 + ks * 16);

    f32x16 p0 = {}, p1 = {};
#pragma unroll
    for (int ds = 0; ds < 4; ++ds)
      p0 = __builtin_amdgcn_mfma_f32_32x32x16_bf16(kf[0][ds], qf[ds], p0, 0, 0, 0);
#pragma unroll
    for (int ds = 0; ds < 4; ++ds)
      p1 = __builtin_amdgcn_mfma_f32_32x32x16_bf16(kf[1][ds], qf[ds], p1, 0, 0, 0);

    if (masked) {   // general-mask slow path (log2-scaled bias)
#pragma unroll
      for (int rr = 0; rr < 4; ++rr) {
        f32x4 mb0 = *(const f32x4*)(mask + k0 + rr * 8 + hi * 4);
        f32x4 mb1 = *(const f32x4*)(mask + k0 + 32 + rr * 8 + hi * 4);
#pragma unroll
        for (int j = 0; j < 4; ++j) {
          p0[rr * 4 + j] += (1.f - mb0[j]) * -1.442695041e9f;
          p1[rr * 4 + j] += (1.f - mb1[j]) * -1.442695041e9f;
        }
      }
    }
    // tile max over this lane's 32 keys, then exchange halves
    float tm = p0[0];
#pragma unroll
    for (int r = 1; r < 16; ++r) tm = fmaxf(tm, p0[r]);
#pragma unroll
    for (int r = 0; r < 16; ++r) tm = fmaxf(tm, p1[r]);
    tm = fmaxf(tm, __shfl_xor(tm, 32));
    // defer-max: only rescale when tile max grew past threshold (log2 units)
    if (!__all(tm <= m_run + 8.f)) {
      float m_new = fmaxf(m_run, tm);
      float alpha = exp2f(m_run - m_new);
      l_run *= alpha;
      m_run = m_new;
#pragma unroll
      for (int r = 0; r < 16; ++r) {
        float a = __shfl(alpha, (r & 3) + 8 * (r >> 2) + 4 * hi);
        acc0[r] *= a; acc1[r] *= a;
      }
    }
    float ts = 0.f;
#pragma unroll
    for (int r = 0; r < 16; ++r) { float e = exp2f(p0[r] - m_run); p0[r] = e; ts += e; }
#pragma unroll
    for (int r = 0; r < 16; ++r) { float e = exp2f(p1[r] - m_run); p1[r] = e; ts += e; }
    ts += __shfl_xor(ts, 32);
    l_run += ts;

    // pack 8 S-regs (16 keys of one 32-key block) into the PV A-fragment.
    // Lane(hi=0) holds keys {0..3, 8..11}, lane(hi=1) holds {4..7, 12..15}
    // (within the 16-key slice). A-frag needs keys hi*8 + [0,8):
    //   word0 = keys(0,1)/(8,9)   = hi ? partner(W2) : own(W0)
    //   word1 = keys(2,3)/(10,11) = hi ? partner(W3) : own(W1)
    //   word2 = keys(4,5)/(12,13) = hi ? own(W2)     : partner(W0)
    //   word3 = keys(6,7)/(14,15) = hi ? own(W3)     : partner(W1)
    auto pack8 = [&](float a0, float a1, float a2, float a3,
                     float a4, float a5, float a6, float a7) -> bf16x8 {
      unsigned int W0 = pk2(a0, a1), W1 = pk2(a2, a3);
      unsigned int W2 = pk2(a4, a5), W3 = pk2(a6, a7);
      unsigned int pW0 = (unsigned int)__shfl_xor((int)W0, 32);
      unsigned int pW1 = (unsigned int)__shfl_xor((int)W1, 32);
      unsigned int pW2 = (unsigned int)__shfl_xor((int)W2, 32);
      unsigned int pW3 = (unsigned int)__shfl_xor((int)W3, 32);
      union { unsigned int u[4]; bf16x8 v; } cv;
      cv.u[0] = hi ? pW2 : W0;
      cv.u[1] = hi ? pW3 : W1;
      cv.u[2] = hi ? W2 : pW0;
      cv.u[3] = hi ? W3 : pW1;
      return cv.v;
    };
    bf16x8 pa;
    pa = pack8(p0[0], p0[1], p0[2], p0[3], p0[4], p0[5], p0[6], p0[7]);
    acc0 = __builtin_amdgcn_mfma_f32_32x32x16_bf16(pa, vf[0][0], acc0, 0, 0, 0);
    acc1 = __builtin_amdgcn_mfma_f32_32x32x16_bf16(pa, vf[1][0], acc1, 0, 0, 0);
    pa = pack8(p0[8], p0[9], p0[10], p0[11], p0[12], p0[13], p0[14], p0[15]);
    acc0 = __builtin_amdgcn_mfma_f32_32x32x16_bf16(pa, vf[0][1], acc0, 0, 0, 0);
    acc1 = __builtin_amdgcn_mfma_f32_32x32x16_bf16(pa, vf[1][1], acc1, 0, 0, 0);
    pa = pack8(p1[0], p1[1], p1[2], p1[3], p1[4], p1[5], p1[6], p1[7]);
    acc0 = __builtin_amdgcn_mfma_f32_32x32x16_bf16(pa, vf[0][2], acc0, 0, 0, 0);
    acc1 = __builtin_amdgcn_mfma_f32_32x32x16_bf16(pa, vf[1][2], acc1, 0, 0, 0);
    pa = pack8(p1[8], p1[9], p1[10], p1[11], p1[12], p1[13], p1[14], p1[15]);
    acc0 = __builtin_amdgcn_mfma_f32_32x32x16_bf16(pa, vf[0][3], acc0, 0, 0, 0);
    acc1 = __builtin_amdgcn_mfma_f32_32x32x16_bf16(pa, vf[1][3], acc1, 0, 0, 0);
  }

  // epilogue: normalize by l (per output row q = (r&3)+8*(r>>2)+4*hi) and store
  float rin[16];
#pragma unroll
  for (int r = 0; r < 16; ++r) {
    float lq = __shfl(l_run, (r & 3) + 8 * (r >> 2) + 4 * hi);
    rin[r] = 1.f / lq;
  }
#pragma unroll
  for (int r = 0; r < 16; ++r) {
    int qrow = q0 + (r & 3) + 8 * (r >> 2) + 4 * hi;
    size_t base = (size_t)qrow * ED + head * HD + l31;
    ctx[base]      = f2bf(acc0[r] * rin[r]);
    ctx[base + 32] = f2bf(acc1[r] * rin[r]);
  }
}

extern "C" void kernel_launch(void* const* d_in, const int* in_sizes, int n_in,
                              void* d_out, int out_size, void* d_ws, size_t ws_size,
                              hipStream_t stream)
{
  const float* x    = (const float*)d_in[0];
  const float* mask = (const float*)d_in[1];
  const float* wq   = (const float*)d_in[2];
  const float* bq   = (const float*)d_in[3];
  const float* wk   = (const float*)d_in[4];
  const float* bk   = (const float*)d_in[5];
  const float* wv   = (const float*)d_in[6];
  const float* bv   = (const float*)d_in[7];
  const float* wo   = (const float*)d_in[8];
  const float* bo   = (const float*)d_in[9];
  float* out = (float*)d_out;

  char* ws = (char*)d_ws;
  unsigned short* xb    = (unsigned short*)(ws);                 // 6,291,456 B
  unsigned short* wb    = (unsigned short*)(ws + 6291456);       // 3,538,944 B
  unsigned short* wob   = (unsigned short*)(ws + 9830400);       // 1,179,648 B
  float*          biasc = (float*)(ws + 11010048);               // 9,216 B
  unsigned short* qkvb  = (unsigned short*)(ws + 11019264);      // 18,874,368 B
  unsigned short* qrp   = (unsigned short*)(ws + 29893632);      // 6,291,456 B
  unsigned short* krp   = (unsigned short*)(ws + 36185088);      // 6,291,456 B
  unsigned short* vTp   = (unsigned short*)(ws + 42476544);      // 6,291,456 B
  unsigned short* ctxb  = (unsigned short*)(ws + 48768000);      // 6,291,456 B -> 55,059,456 total

  convert_kernel<<<21513, 256, 0, stream>>>(x, wq, wk, wv, wo, bq, bk, bv, xb, wb, wob, biasc);
  gemm_bf16nt<1><<<32 * 18, 256, 0, stream>>>(xb, wb, biasc, qkvb, 4096, 2304, 768, 2304);
  prep_kernel<<<768, 256, 0, stream>>>(qkvb, qrp, krp, vTp);
  attn_kernel<<<1536, 64, 0, stream>>>(qrp, krp, vTp, mask, ctxb);
  gemm_bf16nt<0><<<32 * 6, 256, 0, stream>>>(ctxb, wob, bo, out, 4096, 768, 768, 768);
}